// Round 4
// baseline (102.909 us; speedup 1.0000x reference)
//
#include <hip/hip_runtime.h>
#include <math.h>

#define NB 8
#define NHEADS 8
#define NDK 32
#define NDV 64
#define NSEQ 1024
#define NCIN 256

typedef __attribute__((ext_vector_type(8))) short bf16x8;
typedef __attribute__((ext_vector_type(4))) float f32x4;
typedef __attribute__((ext_vector_type(16))) float f32x16;

#define MFMA16(A, B, C) __builtin_amdgcn_mfma_f32_16x16x32_bf16(A, B, C, 0, 0, 0)
#define MFMA32(A, B, C) __builtin_amdgcn_mfma_f32_32x32x16_bf16(A, B, C, 0, 0, 0)

// log2e folded constants: logits2 = qk * (1/sqrt(32) * log2e) + pe * (sqrt(32) * log2e)
#define SC2 0.2550347873f
#define PE2 8.1611156f

__device__ __forceinline__ short f2bf(float f) {
    union { float f; unsigned u; } v; v.f = f;
    unsigned r = v.u + 0x7FFFu + ((v.u >> 16) & 1u);
    return (short)(r >> 16);
}

__device__ __forceinline__ unsigned cvt_pk_bf16(float lo, float hi) {
    unsigned r;
    asm("v_cvt_pk_bf16_f32 %0, %1, %2" : "=v"(r) : "v"(lo), "v"(hi));
    return r;
}

// ---------------- K0: fold BN into weights, convert to bf16 ----------------
__global__ __launch_bounds__(256) void prep_kernel(
    const float* __restrict__ wq, const float* __restrict__ qg, const float* __restrict__ qb,
    const float* __restrict__ qm, const float* __restrict__ qv,
    const float* __restrict__ wk, const float* __restrict__ kg, const float* __restrict__ kb,
    const float* __restrict__ km, const float* __restrict__ kv,
    const float* __restrict__ wv, const float* __restrict__ vg, const float* __restrict__ vb,
    const float* __restrict__ vm, const float* __restrict__ vv,
    const float* __restrict__ wo,
    short* __restrict__ Wqkv, float* __restrict__ Bqkv, short* __restrict__ Wo)
{
    int row = blockIdx.x, t = threadIdx.x;
    if (row < 1024) {
        const float *w, *g, *be, *mu, *va; int o;
        if (row < 256)      { w = wq; o = row;       g = qg; be = qb; mu = qm; va = qv; }
        else if (row < 512) { w = wk; o = row - 256; g = kg; be = kb; mu = km; va = kv; }
        else                { w = wv; o = row - 512; g = vg; be = vb; mu = vm; va = vv; }
        float inv = g[o] * rsqrtf(va[o] + 1e-5f);
        Wqkv[row * NCIN + t] = f2bf(w[o * NCIN + t] * inv);
        if (t == 0) Bqkv[row] = be[o] - mu[o] * inv;
    } else {
        int o = row - 1024;
        Wo[o * 512 + t]       = f2bf(wo[o * 512 + t]);
        Wo[o * 512 + 256 + t] = f2bf(wo[o * 512 + 256 + t]);
    }
}

// ---------------- K1: x (b,c,p) f32 -> Xt (b,p,c) bf16 ----------------
__global__ __launch_bounds__(256) void transpose_kernel(const float* __restrict__ x, short* __restrict__ Xt)
{
    __shared__ float tile[64][65];
    int b = blockIdx.z, p0 = blockIdx.x * 64, c0 = blockIdx.y * 64;
    int t = threadIdx.x, tp = t & 63, tr = t >> 6;
    const float* xb = x + ((size_t)b * NCIN + c0) * NSEQ + p0;
#pragma unroll
    for (int i = 0; i < 16; ++i) {
        int cl = tr * 16 + i;
        tile[cl][tp] = xb[(size_t)cl * NSEQ + tp];
    }
    __syncthreads();
    short* xt = Xt + ((size_t)b * NSEQ + p0) * NCIN + c0;
#pragma unroll
    for (int i = 0; i < 16; ++i) {
        int pl = tr * 16 + i;
        xt[(size_t)pl * NCIN + tp] = f2bf(tile[tp][pl]);
    }
}

// ---------------- K2: QKV projection GEMM ----------------
__global__ __launch_bounds__(256) void qkv_gemm(
    const short* __restrict__ Xt, const short* __restrict__ Wqkv, const float* __restrict__ Bqkv,
    short* __restrict__ Qo, short* __restrict__ Ko, short* __restrict__ Vto)
{
    __shared__ short At[128][40];
    __shared__ short Bt[128][40];
    int b = blockIdx.z, p0 = blockIdx.x * 128, o0 = blockIdx.y * 128;
    int t = threadIdx.x, wave = t >> 6, lane = t & 63;
    int wr = wave >> 1, wc = wave & 1, lr = lane & 15, lg = lane >> 4;

    const short* Abase = Xt + ((size_t)b * NSEQ + p0) * NCIN;
    const short* Bbase = Wqkv + (size_t)o0 * NCIN;

    f32x4 acc[4][4];
#pragma unroll
    for (int m = 0; m < 4; ++m)
#pragma unroll
        for (int n = 0; n < 4; ++n) acc[m][n] = (f32x4){0.f, 0.f, 0.f, 0.f};

    int srow = t >> 1, sch = (t & 1) * 16;
    for (int k0 = 0; k0 < NCIN; k0 += 32) {
        const int4* ga = (const int4*)(Abase + (size_t)srow * NCIN + k0 + sch);
        const int4* gb = (const int4*)(Bbase + (size_t)srow * NCIN + k0 + sch);
        int4 a0 = ga[0], a1 = ga[1];
        int4 b0 = gb[0], b1 = gb[1];
        *(int4*)&At[srow][sch]     = a0;
        *(int4*)&At[srow][sch + 8] = a1;
        *(int4*)&Bt[srow][sch]     = b0;
        *(int4*)&Bt[srow][sch + 8] = b1;
        __syncthreads();
        bf16x8 af[4], bfr[4];
#pragma unroll
        for (int m = 0; m < 4; ++m) af[m] = *(const bf16x8*)&At[wr * 64 + m * 16 + lr][lg * 8];
#pragma unroll
        for (int n = 0; n < 4; ++n) bfr[n] = *(const bf16x8*)&Bt[wc * 64 + n * 16 + lr][lg * 8];
#pragma unroll
        for (int m = 0; m < 4; ++m)
#pragma unroll
            for (int n = 0; n < 4; ++n)
                acc[m][n] = MFMA16(af[m], bfr[n], acc[m][n]);
        __syncthreads();
    }

#pragma unroll
    for (int n = 0; n < 4; ++n) {
        int o = o0 + wc * 64 + n * 16 + lr;
        float bias = Bqkv[o];
#pragma unroll
        for (int m = 0; m < 4; ++m) {
            int pr = p0 + wr * 64 + m * 16 + lg * 4;
#pragma unroll
            for (int r = 0; r < 4; ++r) {
                float y = acc[m][n][r] + bias;
                short vv = f2bf(y);
                int p = pr + r;
                if (o < 256) {
                    int hh = o >> 5, d = o & 31;
                    Qo[(((size_t)b * NHEADS + hh) * NSEQ + p) * NDK + d] = vv;
                } else if (o < 512) {
                    int oo = o - 256, hh = oo >> 5, d = oo & 31;
                    Ko[(((size_t)b * NHEADS + hh) * NSEQ + p) * NDK + d] = vv;
                } else {
                    int oo = o - 512, hh = oo >> 6, d = oo & 63;
                    Vto[(((size_t)b * NHEADS + hh) * NDV + d) * NSEQ + p] = vv;
                }
            }
        }
    }
}

// ---------------- K3: flash attention + GELU ----------------
// Swapped-operand 32x32, 4-way KV-split, NO max tracking (m==0: |logits2| << 127
// so exp2 cannot overflow; softmax is shift-invariant). No loop-carried scalar
// except lsum tree + O MFMA accumulators -> tiles pipeline freely (unroll 2).
__global__ __launch_bounds__(256) void attn_kernel(
    const short* __restrict__ Q, const short* __restrict__ K, const short* __restrict__ Vt,
    const float* __restrict__ pos_emb, short* __restrict__ Xg)
{
    __shared__ float pe3[32][63];   // [dr][31 + (q - j)] -- abs folded into build
    __shared__ float lbuf[4][32];
    __shared__ float Oacc[32][68];

    int bid = blockIdx.x;
    int h = bid & 7;                 // head per XCD -> per-XCD K/V set 1.5MB (L2-fit)
    int qt = (bid >> 3) & 31;
    int b = bid >> 8;
    int t = threadIdx.x, wave = t >> 6, l = t & 63, ql = l & 31, hi = l >> 5;

    {   // build replicated bias table (2016 entries, 256 threads)
        int dr = t >> 3, i0 = (t & 7) * 8;
#pragma unroll
        for (int k = 0; k < 8; ++k) {
            int ix = i0 + k;
            if (ix < 63) {
                int dc = ix - 31; dc = dc < 0 ? -dc : dc;
                pe3[dr][ix] = pos_emb[(dr * 32 + dc) * NHEADS + h] * PE2;
            }
        }
    }
    __syncthreads();

    size_t bh = (size_t)b * NHEADS + h;
    const short* Qb = Q + bh * NSEQ * NDK;
    const short* Kb = K + bh * NSEQ * NDK;
    const short* Vb = Vt + bh * NDV * NSEQ;

    int q0 = qt * 32;
    int iq = q0 + ql;
    int qh = ql - 4 * hi + 31;  // pe3 col index = qh - jc_r

    bf16x8 qf0 = *(const bf16x8*)(Qb + (size_t)iq * NDK + hi * 8);
    bf16x8 qf1 = *(const bf16x8*)(Qb + (size_t)iq * NDK + 16 + hi * 8);

    float lsum = 0.f;
    f32x16 O0, O1;
#pragma unroll
    for (int r = 0; r < 16; ++r) { O0[r] = 0.f; O1[r] = 0.f; }

#pragma unroll 2
    for (int jt = 0; jt < 8; ++jt) {
        int j0 = wave * 256 + jt * 32;
        bf16x8 kf0 = *(const bf16x8*)(Kb + (size_t)(j0 + ql) * NDK + hi * 8);
        bf16x8 kf1 = *(const bf16x8*)(Kb + (size_t)(j0 + ql) * NDK + 16 + hi * 8);
        f32x16 S;
#pragma unroll
        for (int r = 0; r < 16; ++r) S[r] = 0.f;
        S = MFMA32(kf0, qf0, S);
        S = MFMA32(kf1, qf1, S);

        // V^T fragments issued early: L2 latency hides under softmax
        bf16x8 vf[4];
#pragma unroll
        for (int dn = 0; dn < 2; ++dn)
#pragma unroll
            for (int ks = 0; ks < 2; ++ks)
                vf[dn * 2 + ks] = *(const bf16x8*)(Vb + (size_t)(dn * 32 + ql) * NSEQ + j0 + ks * 16 + hi * 8);

        int drb = qt - (j0 >> 5); drb = drb < 0 ? -drb : drb;  // wave-uniform
        const float* per = pe3[drb];
#pragma unroll
        for (int r = 0; r < 16; ++r) {
            int jcr = (r & 3) + 8 * (r >> 2);
            S[r] = fmaf(S[r], SC2, per[qh - jcr]);
        }

        // P = exp2(logits2), no shift
#pragma unroll
        for (int r = 0; r < 16; ++r) S[r] = __builtin_amdgcn_exp2f(S[r]);

        // lsum: 15-add tree (log depth), single loop-carried add
        {
            float a0 = S[0] + S[1],   a1 = S[2] + S[3];
            float a2 = S[4] + S[5],   a3 = S[6] + S[7];
            float a4 = S[8] + S[9],   a5 = S[10] + S[11];
            float a6 = S[12] + S[13], a7 = S[14] + S[15];
            float b0 = a0 + a1, b1 = a2 + a3, b2 = a4 + a5, b3 = a6 + a7;
            lsum += (b0 + b1) + (b2 + b3);
        }

        // pack P pairs (v_cvt_pk_bf16_f32)
        unsigned pk[4][2];
#pragma unroll
        for (int a = 0; a < 4; ++a)
#pragma unroll
            for (int u = 0; u < 2; ++u)
                pk[a][u] = cvt_pk_bf16(S[4 * a + 2 * u], S[4 * a + 2 * u + 1]);

        // rebuild P fragment in-register (partner exchange via lane^32); PV is
        // a pure accumulate -> off the critical path
#pragma unroll
        for (int ks = 0; ks < 2; ++ks) {
            unsigned s0 = hi ? pk[2 * ks][0] : pk[2 * ks + 1][0];
            unsigned s1 = hi ? pk[2 * ks][1] : pk[2 * ks + 1][1];
            unsigned w0 = (unsigned)__shfl_xor((int)s0, 32);
            unsigned w1 = (unsigned)__shfl_xor((int)s1, 32);
            union { bf16x8 v; unsigned u[4]; } pf;
            pf.u[0] = hi ? w0 : pk[2 * ks][0];
            pf.u[1] = hi ? w1 : pk[2 * ks][1];
            pf.u[2] = hi ? pk[2 * ks + 1][0] : w0;
            pf.u[3] = hi ? pk[2 * ks + 1][1] : w1;
            O0 = MFMA32(vf[ks], pf.v, O0);
            O1 = MFMA32(vf[2 + ks], pf.v, O1);
        }
    }

    // combine halves (each half summed its own 16 j's)
    lsum += __shfl_xor(lsum, 32);

    // ---- merge 4 wave-partials (no max alignment needed) ----
    if (hi == 0) lbuf[wave][ql] = lsum;
#pragma unroll
    for (int w = 0; w < 4; ++w) {
        if (w == 0) __syncthreads();
        if (wave == w) {
#pragma unroll
            for (int dn = 0; dn < 2; ++dn)
#pragma unroll
                for (int a = 0; a < 4; ++a) {
                    float* dst = &Oacc[ql][dn * 32 + 8 * a + 4 * hi];
#pragma unroll
                    for (int bb = 0; bb < 4; ++bb) {
                        float v = dn ? O1[4 * a + bb] : O0[4 * a + bb];
                        if (w == 0) dst[bb] = v; else dst[bb] += v;
                    }
                }
        }
        __syncthreads();
    }

    // ---- cooperative GELU + store: thread t -> q = t>>3, 8 d-values ----
    {
        int qq = t >> 3, dblk = (t & 7) * 8;
        float lt = lbuf[0][qq] + lbuf[1][qq] + lbuf[2][qq] + lbuf[3][qq];
        float inv = 1.0f / lt;
        unsigned pkw[4];
#pragma unroll
        for (int e = 0; e < 4; ++e) {
            float v0 = Oacc[qq][dblk + 2 * e] * inv;
            float v1 = Oacc[qq][dblk + 2 * e + 1] * inv;
            v0 = 0.5f * v0 * (1.f + erff(v0 * 0.70710678118654752f));
            v1 = 0.5f * v1 * (1.f + erff(v1 * 0.70710678118654752f));
            pkw[e] = cvt_pk_bf16(v0, v1);
        }
        *(int4*)(Xg + ((size_t)b * NSEQ + q0 + qq) * 512 + h * 64 + dblk) = *(int4*)pkw;
    }
}

// ---------------- K4: output projection + bias + BN (128x64 tiles) ----------------
__global__ __launch_bounds__(256) void out_gemm(
    const short* __restrict__ Xg, const short* __restrict__ Wo,
    const float* __restrict__ bo, const float* __restrict__ og, const float* __restrict__ ob,
    const float* __restrict__ om, const float* __restrict__ ov,
    float* __restrict__ out)
{
    __shared__ short At[128][40];
    __shared__ short Bt[64][40];
    int mt = blockIdx.x, nt = blockIdx.y;
    int t = threadIdx.x, wave = t >> 6, lane = t & 63;
    int wr = wave >> 1, wc = wave & 1, lr = lane & 15, lg = lane >> 4;
    int row0 = mt * 128, o0 = nt * 64;

    f32x4 acc[4][2];
#pragma unroll
    for (int m = 0; m < 4; ++m)
#pragma unroll
        for (int n = 0; n < 2; ++n) acc[m][n] = (f32x4){0.f, 0.f, 0.f, 0.f};

    int rowA = t >> 1, chA = (t & 1) * 16;
    int rowB = t >> 2, chB = (t & 3) * 8;
    for (int k0 = 0; k0 < 512; k0 += 32) {
        const int4* ga = (const int4*)(Xg + ((size_t)(row0 + rowA)) * 512 + k0 + chA);
        int4 a0 = ga[0], a1 = ga[1];
        int4 b0 = *(const int4*)(Wo + ((size_t)(o0 + rowB)) * 512 + k0 + chB);
        *(int4*)&At[rowA][chA]     = a0;
        *(int4*)&At[rowA][chA + 8] = a1;
        *(int4*)&Bt[rowB][chB]     = b0;
        __syncthreads();
        bf16x8 af[4], bfr[2];
#pragma unroll
        for (int m = 0; m < 4; ++m) af[m] = *(const bf16x8*)&At[wr * 64 + m * 16 + lr][lg * 8];
#pragma unroll
        for (int n = 0; n < 2; ++n) bfr[n] = *(const bf16x8*)&Bt[wc * 32 + n * 16 + lr][lg * 8];
#pragma unroll
        for (int m = 0; m < 4; ++m)
#pragma unroll
            for (int n = 0; n < 2; ++n)
                acc[m][n] = MFMA16(af[m], bfr[n], acc[m][n]);
        __syncthreads();
    }

    int b = row0 >> 10;
    int pbase = row0 & 1023;
#pragma unroll
    for (int n = 0; n < 2; ++n) {
        int o = o0 + wc * 32 + n * 16 + lr;
        float inv = og[o] * rsqrtf(ov[o] + 1e-5f);
        float off = bo[o] * inv + ob[o] - om[o] * inv;
        float* dst = out + ((size_t)b * 256 + o) * 1024 + pbase;
#pragma unroll
        for (int m = 0; m < 4; ++m)
#pragma unroll
            for (int r = 0; r < 4; ++r) {
                int p = wr * 64 + m * 16 + lg * 4 + r;
                dst[p] = acc[m][n][r] * inv + off;
            }
    }
}

// ---------------- launch ----------------
extern "C" void kernel_launch(void* const* d_in, const int* in_sizes, int n_in,
                              void* d_out, int out_size, void* d_ws, size_t ws_size,
                              hipStream_t stream) {
    const float* x     = (const float*)d_in[0];
    const float* wq    = (const float*)d_in[1];
    const float* qgam  = (const float*)d_in[2];
    const float* qbet  = (const float*)d_in[3];
    const float* qmu   = (const float*)d_in[4];
    const float* qvar  = (const float*)d_in[5];
    const float* wk    = (const float*)d_in[6];
    const float* kgam  = (const float*)d_in[7];
    const float* kbet  = (const float*)d_in[8];
    const float* kmu   = (const float*)d_in[9];
    const float* kvar  = (const float*)d_in[10];
    const float* wv    = (const float*)d_in[11];
    const float* vgam  = (const float*)d_in[12];
    const float* vbet  = (const float*)d_in[13];
    const float* vmu   = (const float*)d_in[14];
    const float* vvar  = (const float*)d_in[15];
    const float* wo    = (const float*)d_in[16];
    const float* bo    = (const float*)d_in[17];
    const float* ogam  = (const float*)d_in[18];
    const float* obet  = (const float*)d_in[19];
    const float* omu   = (const float*)d_in[20];
    const float* ovar  = (const float*)d_in[21];
    const float* pos_emb = (const float*)d_in[22];
    // d_in[23] pos_indices: recomputed analytically in-kernel

    char* ws = (char*)d_ws;
    short* Wqkv = (short*)(ws + 0);          // 524288
    float* Bqkv = (float*)(ws + 524288);     // 4096
    short* Wo   = (short*)(ws + 528384);     // 262144
    short* Xt   = (short*)(ws + 790528);     // 4 MB
    short* Qd   = (short*)(ws + 4984832);    // 4 MB
    short* Kd   = (short*)(ws + 9179136);    // 4 MB
    short* Vtd  = (short*)(ws + 13373440);   // 8 MB
    short* Xg   = (short*)(ws + 21762048);   // 8 MB

    prep_kernel<<<1280, 256, 0, stream>>>(wq, qgam, qbet, qmu, qvar,
                                          wk, kgam, kbet, kmu, kvar,
                                          wv, vgam, vbet, vmu, vvar,
                                          wo, Wqkv, Bqkv, Wo);
    transpose_kernel<<<dim3(16, 4, NB), 256, 0, stream>>>(x, Xt);
    qkv_gemm<<<dim3(8, 8, NB), 256, 0, stream>>>(Xt, Wqkv, Bqkv, Qd, Kd, Vtd);
    attn_kernel<<<2048, 256, 0, stream>>>(Qd, Kd, Vtd, pos_emb, Xg);
    out_gemm<<<dim3(64, 4), 256, 0, stream>>>(Xg, Wo, bo, ogam, obet, omu, ovar, (float*)d_out);
}

// Round 5
// 80.870 us; speedup vs baseline: 1.2725x; 1.2725x over previous
//
#include <hip/hip_runtime.h>
#include <math.h>

#define NB 8
#define NHEADS 8
#define NDK 32
#define NDV 64
#define NSEQ 1024
#define NCIN 256

typedef __attribute__((ext_vector_type(8))) short bf16x8;
typedef __attribute__((ext_vector_type(4))) float f32x4;
typedef __attribute__((ext_vector_type(16))) float f32x16;

#define MFMA16(A, B, C) __builtin_amdgcn_mfma_f32_16x16x32_bf16(A, B, C, 0, 0, 0)
#define MFMA32(A, B, C) __builtin_amdgcn_mfma_f32_32x32x16_bf16(A, B, C, 0, 0, 0)

// log2e folded constants: logits2 = qk * (1/sqrt(32) * log2e) + pe * (sqrt(32) * log2e)
#define SC2 0.2550347873f
#define PE2 8.1611156f

__device__ __forceinline__ short f2bf(float f) {
    union { float f; unsigned u; } v; v.f = f;
    unsigned r = v.u + 0x7FFFu + ((v.u >> 16) & 1u);
    return (short)(r >> 16);
}

__device__ __forceinline__ unsigned cvt_pk_bf16(float lo, float hi) {
    unsigned r;
    asm("v_cvt_pk_bf16_f32 %0, %1, %2" : "=v"(r) : "v"(lo), "v"(hi));
    return r;
}

// ---------------- K0: fold BN into weights, convert to bf16 ----------------
__global__ __launch_bounds__(256) void prep_kernel(
    const float* __restrict__ wq, const float* __restrict__ qg, const float* __restrict__ qb,
    const float* __restrict__ qm, const float* __restrict__ qv,
    const float* __restrict__ wk, const float* __restrict__ kg, const float* __restrict__ kb,
    const float* __restrict__ km, const float* __restrict__ kv,
    const float* __restrict__ wv, const float* __restrict__ vg, const float* __restrict__ vb,
    const float* __restrict__ vm, const float* __restrict__ vv,
    const float* __restrict__ wo,
    short* __restrict__ Wqkv, float* __restrict__ Bqkv, short* __restrict__ Wo)
{
    int row = blockIdx.x, t = threadIdx.x;
    if (row < 1024) {
        const float *w, *g, *be, *mu, *va; int o;
        if (row < 256)      { w = wq; o = row;       g = qg; be = qb; mu = qm; va = qv; }
        else if (row < 512) { w = wk; o = row - 256; g = kg; be = kb; mu = km; va = kv; }
        else                { w = wv; o = row - 512; g = vg; be = vb; mu = vm; va = vv; }
        float inv = g[o] * rsqrtf(va[o] + 1e-5f);
        Wqkv[row * NCIN + t] = f2bf(w[o * NCIN + t] * inv);
        if (t == 0) Bqkv[row] = be[o] - mu[o] * inv;
    } else {
        int o = row - 1024;
        Wo[o * 512 + t]       = f2bf(wo[o * 512 + t]);
        Wo[o * 512 + 256 + t] = f2bf(wo[o * 512 + 256 + t]);
    }
}

// ---------------- K1: x (b,c,p) f32 -> Xt (b,p,c) bf16 ----------------
__global__ __launch_bounds__(256) void transpose_kernel(const float* __restrict__ x, short* __restrict__ Xt)
{
    __shared__ float tile[64][65];
    int b = blockIdx.z, p0 = blockIdx.x * 64, c0 = blockIdx.y * 64;
    int t = threadIdx.x, tp = t & 63, tr = t >> 6;
    const float* xb = x + ((size_t)b * NCIN + c0) * NSEQ + p0;
#pragma unroll
    for (int i = 0; i < 16; ++i) {
        int cl = tr * 16 + i;
        tile[cl][tp] = xb[(size_t)cl * NSEQ + tp];
    }
    __syncthreads();
    short* xt = Xt + ((size_t)b * NSEQ + p0) * NCIN + c0;
#pragma unroll
    for (int i = 0; i < 16; ++i) {
        int pl = tr * 16 + i;
        xt[(size_t)pl * NCIN + tp] = f2bf(tile[tp][pl]);
    }
}

// ---------------- K2: QKV projection GEMM ----------------
__global__ __launch_bounds__(256) void qkv_gemm(
    const short* __restrict__ Xt, const short* __restrict__ Wqkv, const float* __restrict__ Bqkv,
    short* __restrict__ Qo, short* __restrict__ Ko, short* __restrict__ Vto)
{
    __shared__ short At[128][40];
    __shared__ short Bt[128][40];
    int b = blockIdx.z, p0 = blockIdx.x * 128, o0 = blockIdx.y * 128;
    int t = threadIdx.x, wave = t >> 6, lane = t & 63;
    int wr = wave >> 1, wc = wave & 1, lr = lane & 15, lg = lane >> 4;

    const short* Abase = Xt + ((size_t)b * NSEQ + p0) * NCIN;
    const short* Bbase = Wqkv + (size_t)o0 * NCIN;

    f32x4 acc[4][4];
#pragma unroll
    for (int m = 0; m < 4; ++m)
#pragma unroll
        for (int n = 0; n < 4; ++n) acc[m][n] = (f32x4){0.f, 0.f, 0.f, 0.f};

    int srow = t >> 1, sch = (t & 1) * 16;
    for (int k0 = 0; k0 < NCIN; k0 += 32) {
        const int4* ga = (const int4*)(Abase + (size_t)srow * NCIN + k0 + sch);
        const int4* gb = (const int4*)(Bbase + (size_t)srow * NCIN + k0 + sch);
        int4 a0 = ga[0], a1 = ga[1];
        int4 b0 = gb[0], b1 = gb[1];
        *(int4*)&At[srow][sch]     = a0;
        *(int4*)&At[srow][sch + 8] = a1;
        *(int4*)&Bt[srow][sch]     = b0;
        *(int4*)&Bt[srow][sch + 8] = b1;
        __syncthreads();
        bf16x8 af[4], bfr[4];
#pragma unroll
        for (int m = 0; m < 4; ++m) af[m] = *(const bf16x8*)&At[wr * 64 + m * 16 + lr][lg * 8];
#pragma unroll
        for (int n = 0; n < 4; ++n) bfr[n] = *(const bf16x8*)&Bt[wc * 64 + n * 16 + lr][lg * 8];
#pragma unroll
        for (int m = 0; m < 4; ++m)
#pragma unroll
            for (int n = 0; n < 4; ++n)
                acc[m][n] = MFMA16(af[m], bfr[n], acc[m][n]);
        __syncthreads();
    }

#pragma unroll
    for (int n = 0; n < 4; ++n) {
        int o = o0 + wc * 64 + n * 16 + lr;
        float bias = Bqkv[o];
#pragma unroll
        for (int m = 0; m < 4; ++m) {
            int pr = p0 + wr * 64 + m * 16 + lg * 4;
#pragma unroll
            for (int r = 0; r < 4; ++r) {
                float y = acc[m][n][r] + bias;
                short vv = f2bf(y);
                int p = pr + r;
                if (o < 256) {
                    int hh = o >> 5, d = o & 31;
                    Qo[(((size_t)b * NHEADS + hh) * NSEQ + p) * NDK + d] = vv;
                } else if (o < 512) {
                    int oo = o - 256, hh = oo >> 5, d = oo & 31;
                    Ko[(((size_t)b * NHEADS + hh) * NSEQ + p) * NDK + d] = vv;
                } else {
                    int oo = o - 512, hh = oo >> 6, d = oo & 63;
                    Vto[(((size_t)b * NHEADS + hh) * NDV + d) * NSEQ + p] = vv;
                }
            }
        }
    }
}

// ---------------- K3: flash attention + GELU ----------------
// WG = 4 waves x 32q = 128 q-rows of one (b,h); sweep 1024 keys in 64-key tiles.
// K/V staged cooperatively into padded LDS (coalesced global loads -> 8x fewer
// TCP line-transactions than per-lane fragment loads), double-buffered, loads
// issued one tile ahead. Swapped-operand 32x32 MFMA; no-max softmax (|logits2|
// << 127, shift-invariant). Waves own disjoint q -> no cross-wave merge.
__global__ __launch_bounds__(256) void attn_kernel(
    const short* __restrict__ Q, const short* __restrict__ K, const short* __restrict__ Vt,
    const float* __restrict__ pos_emb, short* __restrict__ Xg)
{
    __shared__ float pe3[32][63];        // [dr][31 + (qcol - jcol)], abs folded
    __shared__ short Klds[2][64][36];    // [buf][key][d], 72B stride (2-way reads)
    __shared__ short Vlds[2][64][68];    // [buf][d][j],  136B stride (2-way reads)
    __shared__ short tb[4][32][68];      // per-wave epilogue transpose

    int bid = blockIdx.x;
    int h = bid & 7;                     // head per XCD: per-XCD K/V set 1.5MB (L2-fit)
    int qt = (bid >> 3) & 7;
    int b = bid >> 6;
    int t = threadIdx.x, wave = t >> 6, l = t & 63, ql = l & 31, hi = l >> 5;

    {   // build replicated bias table (2016 entries, 256 threads)
        int dr = t >> 3, i0 = (t & 7) * 8;
#pragma unroll
        for (int k = 0; k < 8; ++k) {
            int ix = i0 + k;
            if (ix < 63) {
                int dc = ix - 31; dc = dc < 0 ? -dc : dc;
                pe3[dr][ix] = pos_emb[(dr * 32 + dc) * NHEADS + h] * PE2;
            }
        }
    }

    size_t bh = (size_t)b * NHEADS + h;
    const short* Qb = Q + bh * NSEQ * NDK;
    const short* Kb = K + bh * NSEQ * NDK;
    const short* Vb = Vt + bh * NDV * NSEQ;

    int q0 = qt * 128 + wave * 32;
    int iq = q0 + ql;
    int qr = iq >> 5;                    // q row-block = qt*4 + wave
    int qh = ql - 4 * hi + 31;           // pe3 col index = qh - jcr

    bf16x8 qf0 = *(const bf16x8*)(Qb + (size_t)iq * NDK + hi * 8);
    bf16x8 qf1 = *(const bf16x8*)(Qb + (size_t)iq * NDK + 16 + hi * 8);

    // staging index split (per thread): K row t>>2 col (t&3)*8 ; V rows t>>3,+32 col (t&7)*8
    int krow = t >> 2, kcol = (t & 3) * 8;
    int vrow = t >> 3, vcol = (t & 7) * 8;

    // prologue: stage tile 0 into buf 0
    {
        int4 kreg  = *(const int4*)(Kb + (size_t)krow * NDK + kcol);
        int4 vreg0 = *(const int4*)(Vb + (size_t)vrow * NSEQ + vcol);
        int4 vreg1 = *(const int4*)(Vb + (size_t)(vrow + 32) * NSEQ + vcol);
        *(int4*)&Klds[0][krow][kcol] = kreg;
        *(int4*)&Vlds[0][vrow][vcol] = vreg0;
        *(int4*)&Vlds[0][vrow + 32][vcol] = vreg1;
    }
    __syncthreads();   // pe3 + tile 0 ready

    float lsum = 0.f;
    f32x16 O0, O1;
#pragma unroll
    for (int r = 0; r < 16; ++r) { O0[r] = 0.f; O1[r] = 0.f; }

    int cur = 0;
    for (int jt = 0; jt < 16; ++jt) {
        int4 kreg, vreg0, vreg1;
        if (jt < 15) {   // issue next-tile loads early; latency hides under compute
            int j0n = (jt + 1) * 64;
            kreg  = *(const int4*)(Kb + (size_t)(j0n + krow) * NDK + kcol);
            vreg0 = *(const int4*)(Vb + (size_t)vrow * NSEQ + j0n + vcol);
            vreg1 = *(const int4*)(Vb + (size_t)(vrow + 32) * NSEQ + j0n + vcol);
        }

#pragma unroll
        for (int s = 0; s < 2; ++s) {
            int jr = (jt * 64 + s * 32) >> 5;
            bf16x8 kf0 = *(const bf16x8*)&Klds[cur][s * 32 + ql][hi * 8];
            bf16x8 kf1 = *(const bf16x8*)&Klds[cur][s * 32 + ql][16 + hi * 8];
            f32x16 S;
#pragma unroll
            for (int r = 0; r < 16; ++r) S[r] = 0.f;
            S = MFMA32(kf0, qf0, S);
            S = MFMA32(kf1, qf1, S);

            bf16x8 vf[4];
#pragma unroll
            for (int dn = 0; dn < 2; ++dn)
#pragma unroll
                for (int ks = 0; ks < 2; ++ks)
                    vf[dn * 2 + ks] = *(const bf16x8*)&Vlds[cur][dn * 32 + ql][s * 32 + ks * 16 + hi * 8];

            int drb = qr - jr; drb = drb < 0 ? -drb : drb;   // wave-uniform
            const float* per = pe3[drb];
#pragma unroll
            for (int r = 0; r < 16; ++r) {
                int jcr = (r & 3) + 8 * (r >> 2);
                S[r] = fmaf(S[r], SC2, per[qh - jcr]);
            }

            // P = exp2(logits2), no shift
#pragma unroll
            for (int r = 0; r < 16; ++r) S[r] = __builtin_amdgcn_exp2f(S[r]);

            {   // lsum: 15-add tree
                float a0 = S[0] + S[1],   a1 = S[2] + S[3];
                float a2 = S[4] + S[5],   a3 = S[6] + S[7];
                float a4 = S[8] + S[9],   a5 = S[10] + S[11];
                float a6 = S[12] + S[13], a7 = S[14] + S[15];
                float b0 = a0 + a1, b1 = a2 + a3, b2 = a4 + a5, b3 = a6 + a7;
                lsum += (b0 + b1) + (b2 + b3);
            }

            unsigned pk[4][2];
#pragma unroll
            for (int a = 0; a < 4; ++a)
#pragma unroll
                for (int u = 0; u < 2; ++u)
                    pk[a][u] = cvt_pk_bf16(S[4 * a + 2 * u], S[4 * a + 2 * u + 1]);

#pragma unroll
            for (int ks = 0; ks < 2; ++ks) {
                unsigned s0 = hi ? pk[2 * ks][0] : pk[2 * ks + 1][0];
                unsigned s1 = hi ? pk[2 * ks][1] : pk[2 * ks + 1][1];
                unsigned w0 = (unsigned)__shfl_xor((int)s0, 32);
                unsigned w1 = (unsigned)__shfl_xor((int)s1, 32);
                union { bf16x8 v; unsigned u[4]; } pf;
                pf.u[0] = hi ? w0 : pk[2 * ks][0];
                pf.u[1] = hi ? w1 : pk[2 * ks][1];
                pf.u[2] = hi ? pk[2 * ks + 1][0] : w0;
                pf.u[3] = hi ? pk[2 * ks + 1][1] : w1;
                O0 = MFMA32(vf[ks], pf.v, O0);
                O1 = MFMA32(vf[2 + ks], pf.v, O1);
            }
        }

        __syncthreads();   // all waves done reading buf[cur^1]'s successor slot
        if (jt < 15) {
            *(int4*)&Klds[cur ^ 1][krow][kcol] = kreg;
            *(int4*)&Vlds[cur ^ 1][vrow][vcol] = vreg0;
            *(int4*)&Vlds[cur ^ 1][vrow + 32][vcol] = vreg1;
            __syncthreads();
            cur ^= 1;
        }
    }

    lsum += __shfl_xor(lsum, 32);
    float inv = 1.0f / lsum;

    // per-wave epilogue: GELU in regs, transpose via private tb slab, 16B stores
    short (*tw)[68] = tb[wave];
#pragma unroll
    for (int dn = 0; dn < 2; ++dn)
#pragma unroll
        for (int a = 0; a < 4; ++a) {
            short4 w;
#pragma unroll
            for (int bb = 0; bb < 4; ++bb) {
                float v = (dn ? O1[4 * a + bb] : O0[4 * a + bb]) * inv;
                v = 0.5f * v * (1.f + erff(v * 0.70710678118654752f));  // exact GELU
                ((short*)&w)[bb] = f2bf(v);
            }
            *(short4*)&tw[ql][dn * 32 + 8 * a + 4 * hi] = w;
        }
    // wave-private buffer: no barrier needed (compiler inserts lgkmcnt)
#pragma unroll
    for (int c = 0; c < 4; ++c) {
        int4 val = *(const int4*)&tw[ql][(hi * 4 + c) * 8];
        *(int4*)(Xg + ((size_t)b * NSEQ + q0 + ql) * 512 + h * 64 + (hi * 4 + c) * 8) = val;
    }
}

// ---------------- K4: output projection + bias + BN (128x64 tiles) ----------------
__global__ __launch_bounds__(256) void out_gemm(
    const short* __restrict__ Xg, const short* __restrict__ Wo,
    const float* __restrict__ bo, const float* __restrict__ og, const float* __restrict__ ob,
    const float* __restrict__ om, const float* __restrict__ ov,
    float* __restrict__ out)
{
    __shared__ short At[128][40];
    __shared__ short Bt[64][40];
    int mt = blockIdx.x, nt = blockIdx.y;
    int t = threadIdx.x, wave = t >> 6, lane = t & 63;
    int wr = wave >> 1, wc = wave & 1, lr = lane & 15, lg = lane >> 4;
    int row0 = mt * 128, o0 = nt * 64;

    f32x4 acc[4][2];
#pragma unroll
    for (int m = 0; m < 4; ++m)
#pragma unroll
        for (int n = 0; n < 2; ++n) acc[m][n] = (f32x4){0.f, 0.f, 0.f, 0.f};

    int rowA = t >> 1, chA = (t & 1) * 16;
    int rowB = t >> 2, chB = (t & 3) * 8;
    for (int k0 = 0; k0 < 512; k0 += 32) {
        const int4* ga = (const int4*)(Xg + ((size_t)(row0 + rowA)) * 512 + k0 + chA);
        int4 a0 = ga[0], a1 = ga[1];
        int4 b0 = *(const int4*)(Wo + ((size_t)(o0 + rowB)) * 512 + k0 + chB);
        *(int4*)&At[rowA][chA]     = a0;
        *(int4*)&At[rowA][chA + 8] = a1;
        *(int4*)&Bt[rowB][chB]     = b0;
        __syncthreads();
        bf16x8 af[4], bfr[2];
#pragma unroll
        for (int m = 0; m < 4; ++m) af[m] = *(const bf16x8*)&At[wr * 64 + m * 16 + lr][lg * 8];
#pragma unroll
        for (int n = 0; n < 2; ++n) bfr[n] = *(const bf16x8*)&Bt[wc * 32 + n * 16 + lr][lg * 8];
#pragma unroll
        for (int m = 0; m < 4; ++m)
#pragma unroll
            for (int n = 0; n < 2; ++n)
                acc[m][n] = MFMA16(af[m], bfr[n], acc[m][n]);
        __syncthreads();
    }

    int b = row0 >> 10;
    int pbase = row0 & 1023;
#pragma unroll
    for (int n = 0; n < 2; ++n) {
        int o = o0 + wc * 32 + n * 16 + lr;
        float inv = og[o] * rsqrtf(ov[o] + 1e-5f);
        float off = bo[o] * inv + ob[o] - om[o] * inv;
        float* dst = out + ((size_t)b * 256 + o) * 1024 + pbase;
#pragma unroll
        for (int m = 0; m < 4; ++m)
#pragma unroll
            for (int r = 0; r < 4; ++r) {
                int p = wr * 64 + m * 16 + lg * 4 + r;
                dst[p] = acc[m][n][r] * inv + off;
            }
    }
}

// ---------------- launch ----------------
extern "C" void kernel_launch(void* const* d_in, const int* in_sizes, int n_in,
                              void* d_out, int out_size, void* d_ws, size_t ws_size,
                              hipStream_t stream) {
    const float* x     = (const float*)d_in[0];
    const float* wq    = (const float*)d_in[1];
    const float* qgam  = (const float*)d_in[2];
    const float* qbet  = (const float*)d_in[3];
    const float* qmu   = (const float*)d_in[4];
    const float* qvar  = (const float*)d_in[5];
    const float* wk    = (const float*)d_in[6];
    const float* kgam  = (const float*)d_in[7];
    const float* kbet  = (const float*)d_in[8];
    const float* kmu   = (const float*)d_in[9];
    const float* kvar  = (const float*)d_in[10];
    const float* wv    = (const float*)d_in[11];
    const float* vgam  = (const float*)d_in[12];
    const float* vbet  = (const float*)d_in[13];
    const float* vmu   = (const float*)d_in[14];
    const float* vvar  = (const float*)d_in[15];
    const float* wo    = (const float*)d_in[16];
    const float* bo    = (const float*)d_in[17];
    const float* ogam  = (const float*)d_in[18];
    const float* obet  = (const float*)d_in[19];
    const float* omu   = (const float*)d_in[20];
    const float* ovar  = (const float*)d_in[21];
    const float* pos_emb = (const float*)d_in[22];
    // d_in[23] pos_indices: recomputed analytically in-kernel

    char* ws = (char*)d_ws;
    short* Wqkv = (short*)(ws + 0);          // 524288
    float* Bqkv = (float*)(ws + 524288);     // 4096
    short* Wo   = (short*)(ws + 528384);     // 262144
    short* Xt   = (short*)(ws + 790528);     // 4 MB
    short* Qd   = (short*)(ws + 4984832);    // 4 MB
    short* Kd   = (short*)(ws + 9179136);    // 4 MB
    short* Vtd  = (short*)(ws + 13373440);   // 8 MB
    short* Xg   = (short*)(ws + 21762048);   // 8 MB

    prep_kernel<<<1280, 256, 0, stream>>>(wq, qgam, qbet, qmu, qvar,
                                          wk, kgam, kbet, kmu, kvar,
                                          wv, vgam, vbet, vmu, vvar,
                                          wo, Wqkv, Bqkv, Wo);
    transpose_kernel<<<dim3(16, 4, NB), 256, 0, stream>>>(x, Xt);
    qkv_gemm<<<dim3(8, 8, NB), 256, 0, stream>>>(Xt, Wqkv, Bqkv, Qd, Kd, Vtd);
    attn_kernel<<<512, 256, 0, stream>>>(Qd, Kd, Vtd, pos_emb, Xg);
    out_gemm<<<dim3(64, 4), 256, 0, stream>>>(Xg, Wo, bo, ogam, obet, omu, ovar, (float*)d_out);
}

// Round 6
// 80.074 us; speedup vs baseline: 1.2852x; 1.0099x over previous
//
#include <hip/hip_runtime.h>
#include <math.h>

#define NB 8
#define NHEADS 8
#define NDK 32
#define NDV 64
#define NSEQ 1024
#define NCIN 256

typedef __attribute__((ext_vector_type(8))) short bf16x8;
typedef __attribute__((ext_vector_type(4))) float f32x4;
typedef __attribute__((ext_vector_type(16))) float f32x16;

#define MFMA16(A, B, C) __builtin_amdgcn_mfma_f32_16x16x32_bf16(A, B, C, 0, 0, 0)
#define MFMA32(A, B, C) __builtin_amdgcn_mfma_f32_32x32x16_bf16(A, B, C, 0, 0, 0)

// log2e folded constants: logits2 = qk * (1/sqrt(32) * log2e) + pe * (sqrt(32) * log2e)
#define SC2 0.2550347873f
#define PE2 8.1611156f

__device__ __forceinline__ short f2bf(float f) {
    union { float f; unsigned u; } v; v.f = f;
    unsigned r = v.u + 0x7FFFu + ((v.u >> 16) & 1u);
    return (short)(r >> 16);
}

__device__ __forceinline__ unsigned cvt_pk_bf16(float lo, float hi) {
    unsigned r;
    asm("v_cvt_pk_bf16_f32 %0, %1, %2" : "=v"(r) : "v"(lo), "v"(hi));
    return r;
}

// ---------------- K0: fold BN into weights, convert to bf16 ----------------
__global__ __launch_bounds__(256) void prep_kernel(
    const float* __restrict__ wq, const float* __restrict__ qg, const float* __restrict__ qb,
    const float* __restrict__ qm, const float* __restrict__ qv,
    const float* __restrict__ wk, const float* __restrict__ kg, const float* __restrict__ kb,
    const float* __restrict__ km, const float* __restrict__ kv,
    const float* __restrict__ wv, const float* __restrict__ vg, const float* __restrict__ vb,
    const float* __restrict__ vm, const float* __restrict__ vv,
    const float* __restrict__ wo,
    short* __restrict__ Wqkv, float* __restrict__ Bqkv, short* __restrict__ Wo)
{
    int row = blockIdx.x, t = threadIdx.x;
    if (row < 1024) {
        const float *w, *g, *be, *mu, *va; int o;
        if (row < 256)      { w = wq; o = row;       g = qg; be = qb; mu = qm; va = qv; }
        else if (row < 512) { w = wk; o = row - 256; g = kg; be = kb; mu = km; va = kv; }
        else                { w = wv; o = row - 512; g = vg; be = vb; mu = vm; va = vv; }
        float inv = g[o] * rsqrtf(va[o] + 1e-5f);
        Wqkv[row * NCIN + t] = f2bf(w[o * NCIN + t] * inv);
        if (t == 0) Bqkv[row] = be[o] - mu[o] * inv;
    } else {
        int o = row - 1024;
        Wo[o * 512 + t]       = f2bf(wo[o * 512 + t]);
        Wo[o * 512 + 256 + t] = f2bf(wo[o * 512 + 256 + t]);
    }
}

// ---------------- K1: x (b,c,p) f32 -> Xt (b,p,c) bf16 ----------------
__global__ __launch_bounds__(256) void transpose_kernel(const float* __restrict__ x, short* __restrict__ Xt)
{
    __shared__ float tile[64][65];
    int b = blockIdx.z, p0 = blockIdx.x * 64, c0 = blockIdx.y * 64;
    int t = threadIdx.x, tp = t & 63, tr = t >> 6;
    const float* xb = x + ((size_t)b * NCIN + c0) * NSEQ + p0;
#pragma unroll
    for (int i = 0; i < 16; ++i) {
        int cl = tr * 16 + i;
        tile[cl][tp] = xb[(size_t)cl * NSEQ + tp];
    }
    __syncthreads();
    short* xt = Xt + ((size_t)b * NSEQ + p0) * NCIN + c0;
#pragma unroll
    for (int i = 0; i < 16; ++i) {
        int pl = tr * 16 + i;
        xt[(size_t)pl * NCIN + tp] = f2bf(tile[tp][pl]);
    }
}

// ---------------- K2: QKV projection GEMM ----------------
__global__ __launch_bounds__(256) void qkv_gemm(
    const short* __restrict__ Xt, const short* __restrict__ Wqkv, const float* __restrict__ Bqkv,
    short* __restrict__ Qo, short* __restrict__ Ko, short* __restrict__ Vto)
{
    __shared__ short At[128][40];
    __shared__ short Bt[128][40];
    int b = blockIdx.z, p0 = blockIdx.x * 128, o0 = blockIdx.y * 128;
    int t = threadIdx.x, wave = t >> 6, lane = t & 63;
    int wr = wave >> 1, wc = wave & 1, lr = lane & 15, lg = lane >> 4;

    const short* Abase = Xt + ((size_t)b * NSEQ + p0) * NCIN;
    const short* Bbase = Wqkv + (size_t)o0 * NCIN;

    f32x4 acc[4][4];
#pragma unroll
    for (int m = 0; m < 4; ++m)
#pragma unroll
        for (int n = 0; n < 4; ++n) acc[m][n] = (f32x4){0.f, 0.f, 0.f, 0.f};

    int srow = t >> 1, sch = (t & 1) * 16;
    for (int k0 = 0; k0 < NCIN; k0 += 32) {
        const int4* ga = (const int4*)(Abase + (size_t)srow * NCIN + k0 + sch);
        const int4* gb = (const int4*)(Bbase + (size_t)srow * NCIN + k0 + sch);
        int4 a0 = ga[0], a1 = ga[1];
        int4 b0 = gb[0], b1 = gb[1];
        *(int4*)&At[srow][sch]     = a0;
        *(int4*)&At[srow][sch + 8] = a1;
        *(int4*)&Bt[srow][sch]     = b0;
        *(int4*)&Bt[srow][sch + 8] = b1;
        __syncthreads();
        bf16x8 af[4], bfr[4];
#pragma unroll
        for (int m = 0; m < 4; ++m) af[m] = *(const bf16x8*)&At[wr * 64 + m * 16 + lr][lg * 8];
#pragma unroll
        for (int n = 0; n < 4; ++n) bfr[n] = *(const bf16x8*)&Bt[wc * 64 + n * 16 + lr][lg * 8];
#pragma unroll
        for (int m = 0; m < 4; ++m)
#pragma unroll
            for (int n = 0; n < 4; ++n)
                acc[m][n] = MFMA16(af[m], bfr[n], acc[m][n]);
        __syncthreads();
    }

#pragma unroll
    for (int n = 0; n < 4; ++n) {
        int o = o0 + wc * 64 + n * 16 + lr;
        float bias = Bqkv[o];
#pragma unroll
        for (int m = 0; m < 4; ++m) {
            int pr = p0 + wr * 64 + m * 16 + lg * 4;
#pragma unroll
            for (int r = 0; r < 4; ++r) {
                float y = acc[m][n][r] + bias;
                short vv = f2bf(y);
                int p = pr + r;
                if (o < 256) {
                    int hh = o >> 5, d = o & 31;
                    Qo[(((size_t)b * NHEADS + hh) * NSEQ + p) * NDK + d] = vv;
                } else if (o < 512) {
                    int oo = o - 256, hh = oo >> 5, d = oo & 31;
                    Ko[(((size_t)b * NHEADS + hh) * NSEQ + p) * NDK + d] = vv;
                } else {
                    int oo = o - 512, hh = oo >> 6, d = oo & 63;
                    Vto[(((size_t)b * NHEADS + hh) * NDV + d) * NSEQ + p] = vv;
                }
            }
        }
    }
}

// ---------------- K3: flash attention + GELU ----------------
// WG = 4 waves x 32q = 128 q-rows of one (b,h); sweep 1024 keys in 64-key tiles.
// K/V staged into padded LDS, double-buffered with ONE barrier per tile.
// Bias: reversed table peR[dr][y]=pe[dr*32+|31-y|]*PE2 -> per-lane base + constant
// ascending offsets (merges to ds_read2_b32). P cross-half exchange via
// v_permlane32_swap_b32 (VALU pipe, off the saturated LDS pipe).
__global__ __launch_bounds__(256) void attn_kernel(
    const short* __restrict__ Q, const short* __restrict__ K, const short* __restrict__ Vt,
    const float* __restrict__ pos_emb, short* __restrict__ Xg)
{
    __shared__ float peR[32][64];
    __shared__ short Klds[2][64][36];    // [buf][key][d]
    __shared__ short Vlds[2][64][68];    // [buf][d][j]
    __shared__ short tb[4][32][68];      // per-wave epilogue transpose

    int bid = blockIdx.x;
    int h = bid & 7;                     // head per XCD: per-XCD K/V set 1.5MB (L2-fit)
    int qt = (bid >> 3) & 7;
    int b = bid >> 6;
    int t = threadIdx.x, wave = t >> 6, l = t & 63, ql = l & 31, hi = l >> 5;

    {   // build reversed bias table: peR[dr][y] = pe[dr*32 + |31-y|] * PE2
        int dr = t >> 3, y0 = (t & 7) * 8;
#pragma unroll
        for (int k = 0; k < 8; ++k) {
            int y = y0 + k;
            if (y < 63) {
                int d = 31 - y; d = d < 0 ? -d : d;
                peR[dr][y] = pos_emb[(dr * 32 + d) * NHEADS + h] * PE2;
            }
        }
    }

    size_t bh = (size_t)b * NHEADS + h;
    const short* Qb = Q + bh * NSEQ * NDK;
    const short* Kb = K + bh * NSEQ * NDK;
    const short* Vb = Vt + bh * NDV * NSEQ;

    int q0 = qt * 128 + wave * 32;
    int iq = q0 + ql;
    int qr = iq >> 5;                    // q row-block
    int pebase = 31 - ql + 4 * hi;       // per-lane col base into peR rows

    bf16x8 qf0 = *(const bf16x8*)(Qb + (size_t)iq * NDK + hi * 8);
    bf16x8 qf1 = *(const bf16x8*)(Qb + (size_t)iq * NDK + 16 + hi * 8);

    int krow = t >> 2, kcol = (t & 3) * 8;
    int vrow = t >> 3, vcol = (t & 7) * 8;

    // prologue: stage tile 0 into buf 0
    {
        int4 kreg  = *(const int4*)(Kb + (size_t)krow * NDK + kcol);
        int4 vreg0 = *(const int4*)(Vb + (size_t)vrow * NSEQ + vcol);
        int4 vreg1 = *(const int4*)(Vb + (size_t)(vrow + 32) * NSEQ + vcol);
        *(int4*)&Klds[0][krow][kcol] = kreg;
        *(int4*)&Vlds[0][vrow][vcol] = vreg0;
        *(int4*)&Vlds[0][vrow + 32][vcol] = vreg1;
    }
    __syncthreads();   // peR + tile 0 ready

    float lsum = 0.f;
    f32x16 O0, O1;
#pragma unroll
    for (int r = 0; r < 16; ++r) { O0[r] = 0.f; O1[r] = 0.f; }

    int cur = 0;
    for (int jt = 0; jt < 16; ++jt) {
        int4 kreg, vreg0, vreg1;
        if (jt < 15) {   // issue next-tile loads early; latency hides under compute
            int j0n = (jt + 1) * 64;
            kreg  = *(const int4*)(Kb + (size_t)(j0n + krow) * NDK + kcol);
            vreg0 = *(const int4*)(Vb + (size_t)vrow * NSEQ + j0n + vcol);
            vreg1 = *(const int4*)(Vb + (size_t)(vrow + 32) * NSEQ + j0n + vcol);
        }

#pragma unroll
        for (int s = 0; s < 2; ++s) {
            int jr = (jt * 64 + s * 32) >> 5;
            bf16x8 kf0 = *(const bf16x8*)&Klds[cur][s * 32 + ql][hi * 8];
            bf16x8 kf1 = *(const bf16x8*)&Klds[cur][s * 32 + ql][16 + hi * 8];
            f32x16 S;
#pragma unroll
            for (int r = 0; r < 16; ++r) S[r] = 0.f;
            S = MFMA32(kf0, qf0, S);
            S = MFMA32(kf1, qf1, S);

            bf16x8 vf[4];
#pragma unroll
            for (int dn = 0; dn < 2; ++dn)
#pragma unroll
                for (int ks = 0; ks < 2; ++ks)
                    vf[dn * 2 + ks] = *(const bf16x8*)&Vlds[cur][dn * 32 + ql][s * 32 + ks * 16 + hi * 8];

            int drb = qr - jr; drb = drb < 0 ? -drb : drb;   // wave-uniform
            const float* per = &peR[drb][pebase];
#pragma unroll
            for (int r = 0; r < 16; ++r) {
                int jcr = (r & 3) + 8 * (r >> 2);
                S[r] = fmaf(S[r], SC2, per[jcr]);
            }

            // P = exp2(logits2), no shift (|logits2| << 127, shift-invariant)
#pragma unroll
            for (int r = 0; r < 16; ++r) S[r] = __builtin_amdgcn_exp2f(S[r]);

            {   // lsum: 15-add tree
                float a0 = S[0] + S[1],   a1 = S[2] + S[3];
                float a2 = S[4] + S[5],   a3 = S[6] + S[7];
                float a4 = S[8] + S[9],   a5 = S[10] + S[11];
                float a6 = S[12] + S[13], a7 = S[14] + S[15];
                float b0 = a0 + a1, b1 = a2 + a3, b2 = a4 + a5, b3 = a6 + a7;
                lsum += (b0 + b1) + (b2 + b3);
            }

            unsigned pk[4][2];
#pragma unroll
            for (int a = 0; a < 4; ++a)
#pragma unroll
                for (int u = 0; u < 2; ++u)
                    pk[a][u] = cvt_pk_bf16(S[4 * a + 2 * u], S[4 * a + 2 * u + 1]);

#pragma unroll
            for (int ks = 0; ks < 2; ++ks) {
                // {u0,u2} = permlane32_swap(pk[2ks][0], pk[2ks+1][0])
                // {u1,u3} = permlane32_swap(pk[2ks][1], pk[2ks+1][1])
                unsigned u0 = pk[2 * ks][0], u2 = pk[2 * ks + 1][0];
                unsigned u1 = pk[2 * ks][1], u3 = pk[2 * ks + 1][1];
                asm("v_permlane32_swap_b32 %0, %1" : "+v"(u0), "+v"(u2));
                asm("v_permlane32_swap_b32 %0, %1" : "+v"(u1), "+v"(u3));
                union { bf16x8 v; unsigned u[4]; } pf;
                pf.u[0] = u0; pf.u[1] = u1; pf.u[2] = u2; pf.u[3] = u3;
                O0 = MFMA32(vf[ks], pf.v, O0);
                O1 = MFMA32(vf[2 + ks], pf.v, O1);
            }
        }

        if (jt < 15) {
            // write next tile to buf[cur^1]: its last readers finished before the
            // PREVIOUS barrier, so one barrier per iteration suffices.
            *(int4*)&Klds[cur ^ 1][krow][kcol] = kreg;
            *(int4*)&Vlds[cur ^ 1][vrow][vcol] = vreg0;
            *(int4*)&Vlds[cur ^ 1][vrow + 32][vcol] = vreg1;
            __syncthreads();
            cur ^= 1;
        }
    }

    lsum += __shfl_xor(lsum, 32);
    float inv = 1.0f / lsum;

    // per-wave epilogue: GELU in regs, transpose via private tb slab, 16B stores
    short (*tw)[68] = tb[wave];
#pragma unroll
    for (int dn = 0; dn < 2; ++dn)
#pragma unroll
        for (int a = 0; a < 4; ++a) {
            short4 w;
#pragma unroll
            for (int bb = 0; bb < 4; ++bb) {
                float v = (dn ? O1[4 * a + bb] : O0[4 * a + bb]) * inv;
                v = 0.5f * v * (1.f + erff(v * 0.70710678118654752f));  // exact GELU
                ((short*)&w)[bb] = f2bf(v);
            }
            *(short4*)&tw[ql][dn * 32 + 8 * a + 4 * hi] = w;
        }
#pragma unroll
    for (int c = 0; c < 4; ++c) {
        int4 val = *(const int4*)&tw[ql][(hi * 4 + c) * 8];
        *(int4*)(Xg + ((size_t)b * NSEQ + q0 + ql) * 512 + h * 64 + (hi * 4 + c) * 8) = val;
    }
}

// ---------------- K4: output projection + bias + BN (128x64 tiles) ----------------
__global__ __launch_bounds__(256) void out_gemm(
    const short* __restrict__ Xg, const short* __restrict__ Wo,
    const float* __restrict__ bo, const float* __restrict__ og, const float* __restrict__ ob,
    const float* __restrict__ om, const float* __restrict__ ov,
    float* __restrict__ out)
{
    __shared__ short At[128][40];
    __shared__ short Bt[64][40];
    int mt = blockIdx.x, nt = blockIdx.y;
    int t = threadIdx.x, wave = t >> 6, lane = t & 63;
    int wr = wave >> 1, wc = wave & 1, lr = lane & 15, lg = lane >> 4;
    int row0 = mt * 128, o0 = nt * 64;

    f32x4 acc[4][2];
#pragma unroll
    for (int m = 0; m < 4; ++m)
#pragma unroll
        for (int n = 0; n < 2; ++n) acc[m][n] = (f32x4){0.f, 0.f, 0.f, 0.f};

    int rowA = t >> 1, chA = (t & 1) * 16;
    int rowB = t >> 2, chB = (t & 3) * 8;
    for (int k0 = 0; k0 < 512; k0 += 32) {
        const int4* ga = (const int4*)(Xg + ((size_t)(row0 + rowA)) * 512 + k0 + chA);
        int4 a0 = ga[0], a1 = ga[1];
        int4 b0 = *(const int4*)(Wo + ((size_t)(o0 + rowB)) * 512 + k0 + chB);
        *(int4*)&At[rowA][chA]     = a0;
        *(int4*)&At[rowA][chA + 8] = a1;
        *(int4*)&Bt[rowB][chB]     = b0;
        __syncthreads();
        bf16x8 af[4], bfr[2];
#pragma unroll
        for (int m = 0; m < 4; ++m) af[m] = *(const bf16x8*)&At[wr * 64 + m * 16 + lr][lg * 8];
#pragma unroll
        for (int n = 0; n < 2; ++n) bfr[n] = *(const bf16x8*)&Bt[wc * 32 + n * 16 + lr][lg * 8];
#pragma unroll
        for (int m = 0; m < 4; ++m)
#pragma unroll
            for (int n = 0; n < 2; ++n)
                acc[m][n] = MFMA16(af[m], bfr[n], acc[m][n]);
        __syncthreads();
    }

    int b = row0 >> 10;
    int pbase = row0 & 1023;
#pragma unroll
    for (int n = 0; n < 2; ++n) {
        int o = o0 + wc * 32 + n * 16 + lr;
        float inv = og[o] * rsqrtf(ov[o] + 1e-5f);
        float off = bo[o] * inv + ob[o] - om[o] * inv;
        float* dst = out + ((size_t)b * 256 + o) * 1024 + pbase;
#pragma unroll
        for (int m = 0; m < 4; ++m)
#pragma unroll
            for (int r = 0; r < 4; ++r) {
                int p = wr * 64 + m * 16 + lg * 4 + r;
                dst[p] = acc[m][n][r] * inv + off;
            }
    }
}

// ---------------- launch ----------------
extern "C" void kernel_launch(void* const* d_in, const int* in_sizes, int n_in,
                              void* d_out, int out_size, void* d_ws, size_t ws_size,
                              hipStream_t stream) {
    const float* x     = (const float*)d_in[0];
    const float* wq    = (const float*)d_in[1];
    const float* qgam  = (const float*)d_in[2];
    const float* qbet  = (const float*)d_in[3];
    const float* qmu   = (const float*)d_in[4];
    const float* qvar  = (const float*)d_in[5];
    const float* wk    = (const float*)d_in[6];
    const float* kgam  = (const float*)d_in[7];
    const float* kbet  = (const float*)d_in[8];
    const float* kmu   = (const float*)d_in[9];
    const float* kvar  = (const float*)d_in[10];
    const float* wv    = (const float*)d_in[11];
    const float* vgam  = (const float*)d_in[12];
    const float* vbet  = (const float*)d_in[13];
    const float* vmu   = (const float*)d_in[14];
    const float* vvar  = (const float*)d_in[15];
    const float* wo    = (const float*)d_in[16];
    const float* bo    = (const float*)d_in[17];
    const float* ogam  = (const float*)d_in[18];
    const float* obet  = (const float*)d_in[19];
    const float* omu   = (const float*)d_in[20];
    const float* ovar  = (const float*)d_in[21];
    const float* pos_emb = (const float*)d_in[22];
    // d_in[23] pos_indices: recomputed analytically in-kernel

    char* ws = (char*)d_ws;
    short* Wqkv = (short*)(ws + 0);          // 524288
    float* Bqkv = (float*)(ws + 524288);     // 4096
    short* Wo   = (short*)(ws + 528384);     // 262144
    short* Xt   = (short*)(ws + 790528);     // 4 MB
    short* Qd   = (short*)(ws + 4984832);    // 4 MB
    short* Kd   = (short*)(ws + 9179136);    // 4 MB
    short* Vtd  = (short*)(ws + 13373440);   // 8 MB
    short* Xg   = (short*)(ws + 21762048);   // 8 MB

    prep_kernel<<<1280, 256, 0, stream>>>(wq, qgam, qbet, qmu, qvar,
                                          wk, kgam, kbet, kmu, kvar,
                                          wv, vgam, vbet, vmu, vvar,
                                          wo, Wqkv, Bqkv, Wo);
    transpose_kernel<<<dim3(16, 4, NB), 256, 0, stream>>>(x, Xt);
    qkv_gemm<<<dim3(8, 8, NB), 256, 0, stream>>>(Xt, Wqkv, Bqkv, Qd, Kd, Vtd);
    attn_kernel<<<512, 256, 0, stream>>>(Qd, Kd, Vtd, pos_emb, Xg);
    out_gemm<<<dim3(64, 4), 256, 0, stream>>>(Xg, Wo, bo, ogam, obet, omu, ovar, (float*)d_out);
}